// Round 6
// baseline (130.248 us; speedup 1.0000x reference)
//
#include <hip/hip_runtime.h>
#include <hip/hip_bf16.h>
#include <stdint.h>

#define N_PTS 16384
#define C_CH  64
#define D_REF 5
#define LOG2E 1.44269504088896340736f
#define IBLOCKS 64        // 256 i per block (4 waves x 4 i-tiles x 16)

typedef __attribute__((ext_vector_type(8))) short bf16x8;
typedef __attribute__((ext_vector_type(4))) float f32x4;

__device__ __forceinline__ unsigned short bf16rn(float v) {
    unsigned u = __builtin_bit_cast(unsigned, v) + 0x8000u;   // round-half-up
    return (unsigned short)(u >> 16);
}
__device__ __forceinline__ float bf16tof(unsigned short h) {
    unsigned u = ((unsigned)h) << 16;
    return __builtin_bit_cast(float, u);
}
__device__ __forceinline__ unsigned pack2bf16(float lo, float hi) {
    unsigned a = __builtin_bit_cast(unsigned, lo) + 0x8000u;
    unsigned b = __builtin_bit_cast(unsigned, hi) + 0x8000u;
    return __builtin_amdgcn_perm(b, a, 0x07060302u);
}
__device__ __forceinline__ float fast_exp2(float x) {
#if __has_builtin(__builtin_amdgcn_exp2f)
    return __builtin_amdgcn_exp2f(x);
#else
    return exp2f(x);
#endif
}

// ---------------------------------------------------------------------------
// merged prep: blocks [0,512) pack ref into G-MFMA A/B fragment buffers,
// blocks [512,768) pack U into PV A-fragments.
//   G = sum_k A_k B_k = log2e*(ri.rj) + hi + hj  via hi/lo bf16 splits.
// PV-DIRECT PERMUTATION (verified R5, bank conflicts = 0, absmax 0.5):
//   A-row w of tile h holds point j = g*32 + (w>>2)*8 + (w&3) + 4h, so the
//   G-pair output regs {g0[0..3], g1[0..3]} on lane (q,m) are exactly
//   S[j = q*8 + t][i = m] == the PV B-operand fragment. No LDS round-trip.
__global__ __launch_bounds__(256) void prep_all(
    const float* __restrict__ U, const float* __restrict__ ref,
    unsigned short* __restrict__ packA, unsigned short* __restrict__ packB,
    unsigned short* __restrict__ utPack)
{
    __shared__ unsigned short tile[64 * 80];
    const int bid = blockIdx.x;
    const int t   = threadIdx.x;

    if (bid < 512) {
        const int gid  = bid * 256 + t;                // 131072 total
        const int half = gid >> 16;                    // 0 = A(j), 1 = B(i)
        const int id   = gid & 0xFFFF;
        const int tile16 = id >> 6;
        const int lane = id & 63;
        const int q    = lane >> 4;
        const int m    = lane & 15;
        // A-side: permuted row->point map; B-side: natural
        const int p = half ? (tile16 * 16 + m)
                           : ((tile16 >> 1) * 32 + (m >> 2) * 8 + (m & 3) + (tile16 & 1) * 4);

        const float* r = ref + (size_t)p * D_REF;
        float rv[5];
        float sq = 0.f;
#pragma unroll
        for (int d = 0; d < 5; ++d) { rv[d] = r[d]; sq += rv[d] * rv[d]; }
        const float h = -0.5f * LOG2E * sq;

        unsigned short bh[5], bl[5];
#pragma unroll
        for (int d = 0; d < 5; ++d) {
            const float base = half ? rv[d] * LOG2E : rv[d];
            bh[d] = bf16rn(base);
            bl[d] = bf16rn(base - bf16tof(bh[d]));
        }
        const unsigned short hh  = bf16rn(h);
        const unsigned short hl  = bf16rn(h - bf16tof(hh));
        const unsigned short one = 0x3F80;

        unsigned short outv[8];
#pragma unroll
        for (int tt = 0; tt < 8; ++tt) {
            const int k = q * 8 + tt;
            unsigned short v = 0;
            if (!half) {
                if      (k < 5)   v = bh[k];
                else if (k < 10)  v = bh[k - 5];
                else if (k < 15)  v = bl[k - 10];
                else if (k == 15) v = hh;
                else if (k == 16) v = hl;
                else if (k <= 18) v = one;
            } else {
                if      (k < 5)   v = bh[k];
                else if (k < 10)  v = bl[k - 5];
                else if (k < 15)  v = bh[k - 10];
                else if (k <= 16) v = one;
                else if (k == 17) v = hh;
                else if (k == 18) v = hl;
            }
            outv[tt] = v;
        }
        unsigned short* dst = (half ? packB : packA) + ((size_t)tile16 * 64 + lane) * 8;
        *(uint4*)dst = *(uint4*)outv;
    } else {
        const int b  = bid - 512;
        const int j0 = b * 64;
        const int c  = t & 63;
        const int jb = t >> 6;
#pragma unroll
        for (int k = 0; k < 16; ++k) {
            const int jr = jb + k * 4;
            tile[c * 80 + jr] = bf16rn(U[(size_t)(j0 + jr) * C_CH + c]);  // coalesced by c
        }
        __syncthreads();
#pragma unroll
        for (int rep = 0; rep < 2; ++rep) {
            const int id   = rep * 256 + t;            // 512 frag-lanes
            const int lane = id & 63;
            const int ct   = (id >> 6) & 3;
            const int kt   = id >> 8;                  // 0..1
            const int m    = lane & 15;
            const int q    = lane >> 4;
            const int cc   = ct * 16 + m;
            const int jloc = kt * 32 + q * 8;
            const uint4 frag = *(const uint4*)&tile[cc * 80 + jloc];
            const int jtile  = b * 2 + kt;
            *(uint4*)&utPack[(((size_t)jtile * 4 + ct) * 64 + lane) * 8] = frag;
        }
    }
}

// ---------------------------------------------------------------------------
// main: BARRIER-FREE. grid = IBLOCKS*JS x 256 thr; wave owns 4 i-tiles.
// No LDS at all: ga/uf fragments load straight from L1/L2 (packA+utPack are
// 3 MB, fully L2-resident; the 4 waves of a block read the same fragments
// nearly in sync -> L1 reuse). ga for kt+1 prefetched explicitly (critical
// path head); uf issued between G-MFMA and PV so its latency hides behind
// exp2. s processed in pairs to bound live VGPRs.
template<int JS>
__global__ __launch_bounds__(256, 4) void lsh_main(
    const float* __restrict__ U,
    const unsigned short* __restrict__ packA,
    const unsigned short* __restrict__ packB,
    const unsigned short* __restrict__ utPack,
    float* __restrict__ part,
    float* __restrict__ out,
    int use_part)
{
    constexpr int UNITS = (N_PTS / JS) / 32;   // jt32 units per block

    const int t    = threadIdx.x;
    const int lane = t & 63;
    const int wave = t >> 6;
    const int q    = lane >> 4;
    const int m    = lane & 15;

    const int ib = blockIdx.x / JS;
    const int js = blockIdx.x % JS;

    bf16x8 bfrag[4];
#pragma unroll
    for (int s = 0; s < 4; ++s) {
        const int itile = ib * 16 + wave * 4 + s;
        bfrag[s] = *(const bf16x8*)(packB + ((size_t)itile * 64 + lane) * 8);
    }

    f32x4 acc[4][4];
#pragma unroll
    for (int s = 0; s < 4; ++s)
#pragma unroll
        for (int ct = 0; ct < 4; ++ct) acc[s][ct] = (f32x4){0.f, 0.f, 0.f, 0.f};

    const unsigned short* pA = packA  + ((size_t)js * UNITS) * 1024 + lane * 8;
    const unsigned short* pU = utPack + ((size_t)js * UNITS) * 2048 + lane * 8;

    bf16x8 ga0 = *(const bf16x8*)pA;
    bf16x8 ga1 = *(const bf16x8*)(pA + 512);

    for (int u = 0; u < UNITS; ++u) {
        // prefetch next unit's ga pair (longest dependency chain head)
        bf16x8 nga0 = ga0, nga1 = ga1;
        if (u + 1 < UNITS) {
            nga0 = *(const bf16x8*)(pA + 1024);
            nga1 = *(const bf16x8*)(pA + 1536);
        }

        const f32x4 z = (f32x4){0.f, 0.f, 0.f, 0.f};
        bf16x8 sfrag[4];
#pragma unroll
        for (int sp = 0; sp < 2; ++sp) {               // s in pairs: bound regs
            f32x4 g0a = __builtin_amdgcn_mfma_f32_16x16x32_bf16(ga0, bfrag[sp*2+0], z, 0, 0, 0);
            f32x4 g1a = __builtin_amdgcn_mfma_f32_16x16x32_bf16(ga1, bfrag[sp*2+0], z, 0, 0, 0);
            f32x4 g0b = __builtin_amdgcn_mfma_f32_16x16x32_bf16(ga0, bfrag[sp*2+1], z, 0, 0, 0);
            f32x4 g1b = __builtin_amdgcn_mfma_f32_16x16x32_bf16(ga1, bfrag[sp*2+1], z, 0, 0, 0);
            union { unsigned u[4]; bf16x8 v; } sa, sb;
            sa.u[0] = pack2bf16(fast_exp2(g0a[0]), fast_exp2(g0a[1]));
            sa.u[1] = pack2bf16(fast_exp2(g0a[2]), fast_exp2(g0a[3]));
            sa.u[2] = pack2bf16(fast_exp2(g1a[0]), fast_exp2(g1a[1]));
            sa.u[3] = pack2bf16(fast_exp2(g1a[2]), fast_exp2(g1a[3]));
            sb.u[0] = pack2bf16(fast_exp2(g0b[0]), fast_exp2(g0b[1]));
            sb.u[1] = pack2bf16(fast_exp2(g0b[2]), fast_exp2(g0b[3]));
            sb.u[2] = pack2bf16(fast_exp2(g1b[0]), fast_exp2(g1b[1]));
            sb.u[3] = pack2bf16(fast_exp2(g1b[2]), fast_exp2(g1b[3]));
            sfrag[sp*2+0] = sa.v;                      // == PV B-frag for 32 j
            sfrag[sp*2+1] = sb.v;
        }
#pragma unroll
        for (int ct = 0; ct < 4; ++ct) {
            const bf16x8 uf = *(const bf16x8*)(pU + ct * 512);
#pragma unroll
            for (int s = 0; s < 4; ++s)
                acc[s][ct] = __builtin_amdgcn_mfma_f32_16x16x32_bf16(
                    uf, sfrag[s], acc[s][ct], 0, 0, 0);
        }

        pA += 1024;
        pU += 2048;
        ga0 = nga0;
        ga1 = nga1;
    }

    if (use_part) {
        // natural (i,c) order: part[js][ib*256 + i_loc][c] -> reduce is linear
        float* dst = part + ((size_t)js * IBLOCKS + ib) * (256 * C_CH);
#pragma unroll
        for (int s = 0; s < 4; ++s) {
            const int i_loc = (wave * 4 + s) * 16 + m;
#pragma unroll
            for (int ct = 0; ct < 4; ++ct)
                *(f32x4*)(dst + i_loc * C_CH + ct * 16 + q * 4) = acc[s][ct];
        }
    } else {
#pragma unroll
        for (int s = 0; s < 4; ++s) {
            const int i_glob = ib * 256 + (wave * 4 + s) * 16 + m;
#pragma unroll
            for (int ct = 0; ct < 4; ++ct)
#pragma unroll
                for (int r2 = 0; r2 < 4; ++r2) {
                    const int c = ct * 16 + q * 4 + r2;
                    float val = acc[s][ct][r2];
                    if (js == 0) val -= U[(size_t)i_glob * C_CH + c];
                    atomicAdd(&out[(size_t)i_glob * C_CH + c], val);
                }
        }
    }
}

// ---------------------------------------------------------------------------
// reduce: out = sum_js part[js] - U; all streams fully coalesced float4.
template<int JS>
__global__ __launch_bounds__(256) void reduce_part(
    const f32x4* __restrict__ part, const f32x4* __restrict__ U,
    f32x4* __restrict__ out)
{
    const int x = blockIdx.x * 256 + threadIdx.x;      // [0, 1<<18)
    f32x4 s = part[x];
#pragma unroll
    for (int js = 1; js < JS; ++js)
        s += part[((size_t)js << 18) + x];
    out[x] = s - U[x];
}

extern "C" void kernel_launch(void* const* d_in, const int* in_sizes, int n_in,
                              void* d_out, int out_size, void* d_ws, size_t ws_size,
                              hipStream_t stream) {
    const float* U   = (const float*)d_in[0];
    const float* ref = (const float*)d_in[1];
    float* out = (float*)d_out;

    // ws: utPack 2 MB | packA 1 MB | packB 1 MB | partials 4 MB * JS
    unsigned short* utPack = (unsigned short*)d_ws;
    unsigned short* packA  = (unsigned short*)((char*)d_ws + (size_t)2 * 1024 * 1024);
    unsigned short* packB  = (unsigned short*)((char*)d_ws + (size_t)3 * 1024 * 1024);
    float*          part   = (float*)((char*)d_ws + (size_t)4 * 1024 * 1024);

    const size_t MB = 1024 * 1024;
    prep_all<<<768, 256, 0, stream>>>(U, ref, packA, packB, utPack);

    if (ws_size >= (4 + 4 * 16) * MB) {
        lsh_main<16><<<IBLOCKS * 16, 256, 0, stream>>>(U, packA, packB, utPack,
                                                       part, out, 1);
        reduce_part<16><<<1024, 256, 0, stream>>>((const f32x4*)part,
                                                  (const f32x4*)U, (f32x4*)out);
    } else if (ws_size >= (4 + 4 * 8) * MB) {
        lsh_main<8><<<IBLOCKS * 8, 256, 0, stream>>>(U, packA, packB, utPack,
                                                     part, out, 1);
        reduce_part<8><<<1024, 256, 0, stream>>>((const f32x4*)part,
                                                 (const f32x4*)U, (f32x4*)out);
    } else {
        hipMemsetAsync(d_out, 0, (size_t)out_size * sizeof(float), stream);
        lsh_main<8><<<IBLOCKS * 8, 256, 0, stream>>>(U, packA, packB, utPack,
                                                     part, out, 0);
    }
}